// Round 9
// baseline (131.176 us; speedup 1.0000x reference)
//
#include <hip/hip_runtime.h>

// LocalWindowAttention B=1 H=8 S=4096 D=128 WIN=256, fp32 in/out.
// QB=32, 4 waves: rows (rg) x window-half (hf). 1024 blocks, XCD head swizzle.
// QK^T: 3-term bf16 hi/lo MFMA, K global->reg with 2-deep prefetch.
// Softmax: split stats, LDS combine (2 barriers).
// PV: bf16 MFMA, V B-frags gathered global->reg with 2-deep prefetch.
// launch_bounds(256,2): register-rich waves (R6's (256,4) forced VGPR=64 + spills).

typedef __bf16 bf16v8 __attribute__((ext_vector_type(8)));
typedef __bf16 bf16x2 __attribute__((ext_vector_type(2)));
typedef float  f32x4  __attribute__((ext_vector_type(4)));

constexpr int QB = 32, DH = 128, WIN = 256;
constexpr int HSUB = 9;                    // 16-key subtiles per wave (half window)
constexpr float SCALE = 0.08838834764831844f;  // 1/sqrt(128)

// LDS: P [32 rows][296 bf16] (stride 592B -> 2-way banks) + m/l stats
constexpr int PSTR  = 296;
constexpr int P_BYTES = QB * PSTR * 2;     // 18944
constexpr int MB_OFF  = P_BYTES;           // float mbuf[2][32]
constexpr int LB_OFF  = MB_OFF + 64 * 4;   // float lbuf[2][32]
constexpr int SMEM_BYTES = LB_OFF + 64 * 4;

union bfu8 { bf16v8 v; bf16x2 p[4]; };

__device__ __forceinline__ void cvt_hilo8(const float4& a, const float4& b,
                                          bf16v8& hi, bf16v8& lo) {
  float x[8] = {a.x, a.y, a.z, a.w, b.x, b.y, b.z, b.w};
  bfu8 H, L;
#pragma unroll
  for (int j = 0; j < 4; ++j) {
    float x0 = x[2 * j], x1 = x[2 * j + 1];
    __bf16 h0 = (__bf16)x0, h1 = (__bf16)x1;
    H.p[j] = bf16x2{h0, h1};
    L.p[j] = bf16x2{(__bf16)(x0 - (float)h0), (__bf16)(x1 - (float)h1)};
  }
  hi = H.v; lo = L.v;
}
__device__ __forceinline__ unsigned short bfbits(float x) {
  union { __bf16 b; unsigned short u; } c; c.b = (__bf16)x; return c.u;
}
#define MFMA(A, B, C) __builtin_amdgcn_mfma_f32_16x16x32_bf16((A), (B), (C), 0, 0, 0)

__global__ __launch_bounds__(256, 2)
void lwa7(const float* __restrict__ qg, const float* __restrict__ kg,
          const float* __restrict__ vg, float* __restrict__ og, int S) {
  __shared__ __align__(16) char smem[SMEM_BYTES];

  const int bid = blockIdx.x;
  const int h   = bid & 7;               // head -> XCD round-robin (L2 locality)
  const int q0  = (bid >> 3) * QB;
  const int tid = threadIdx.x;
  const int wv  = tid >> 6;
  const int lane = tid & 63;
  const int lg  = lane >> 4;
  const int lm  = lane & 15;
  const int rg  = wv & 1;                // row group: rows [16rg, 16rg+16)
  const int hf  = wv >> 1;               // window half: subtiles [9hf, 9hf+9)
  const int ts0 = HSUB * hf;

  const float* qgb = qg + (size_t)h * S * DH;
  const float* kgb = kg + (size_t)h * S * DH;
  const float* vgb = vg + (size_t)h * S * DH;

  // ---- Q fragments (rows q0+16rg+lm), scaled, hi/lo split ----
  bf16v8 qhi[4], qlo[4];
  {
    const float* qrow = qgb + (size_t)(q0 + 16 * rg + lm) * DH;
#pragma unroll
    for (int kc = 0; kc < 4; ++kc) {
      float4 a = *(const float4*)(qrow + 32 * kc + 8 * lg);
      float4 b = *(const float4*)(qrow + 32 * kc + 8 * lg + 4);
      a.x *= SCALE; a.y *= SCALE; a.z *= SCALE; a.w *= SCALE;
      b.x *= SCALE; b.y *= SCALE; b.z *= SCALE; b.w *= SCALE;
      cvt_hilo8(a, b, qhi[kc], qlo[kc]);
    }
  }

  f32x4 acc[HSUB];
#pragma unroll
  for (int s = 0; s < HSUB; ++s) acc[s] = (f32x4){0.f, 0.f, 0.f, 0.f};

  // ---- pass 1: 9 subtiles, K global->reg, 2-deep prefetch ----
  float4 kbuf[2][8];
  auto kload = [&](int s) {
    const int key0 = q0 - WIN + 16 * (ts0 + s);
    if (key0 < 0) return;                // block-uniform
    const float* kr = kgb + (size_t)(key0 + lm) * DH;
#pragma unroll
    for (int kc = 0; kc < 4; ++kc) {
      kbuf[s & 1][2 * kc]     = *(const float4*)(kr + 32 * kc + 8 * lg);
      kbuf[s & 1][2 * kc + 1] = *(const float4*)(kr + 32 * kc + 8 * lg + 4);
    }
  };
  kload(0);
  kload(1);
#pragma unroll
  for (int s = 0; s < HSUB; ++s) {
    const bool live = (q0 - WIN + 16 * (ts0 + s)) >= 0;
    bf16v8 kh[4], kl[4];
    if (live) {
#pragma unroll
      for (int kc = 0; kc < 4; ++kc)     // consume kbuf[s&1] into bf16 regs
        cvt_hilo8(kbuf[s & 1][2 * kc], kbuf[s & 1][2 * kc + 1], kh[kc], kl[kc]);
    }
    if (s + 2 < HSUB) kload(s + 2);      // re-issue the freed buffer
    if (live) {
      f32x4 c = acc[s];
#pragma unroll
      for (int kc = 0; kc < 4; ++kc) {
        c = MFMA(qhi[kc], kh[kc], c);
        c = MFMA(qlo[kc], kh[kc], c);
        c = MFMA(qhi[kc], kl[kc], c);
      }
      acc[s] = c;
    }
  }

  // ---- V 2-deep prefetch: issue chunks 0,1 before softmax (latency hides) ----
  // chunk kc: lane needs V[keyb+8lg+j][64hf+16n+lm], j=0..7, n=0..3
  float vbuf[2][32];
  auto vload = [&](int kc) {
    const int keyb = q0 - WIN + 32 * kc;
    if (keyb < 0) return;                // block-uniform
    const float* vp = vgb + (size_t)(keyb + 8 * lg) * DH + 64 * hf + lm;
#pragma unroll
    for (int n = 0; n < 4; ++n)
#pragma unroll
      for (int j = 0; j < 8; ++j)
        vbuf[kc & 1][8 * n + j] = vp[(size_t)j * DH + 16 * n];
  };
  vload(0);
  vload(1);

  float* mbuf = (float*)(smem + MB_OFF);   // [2][32]
  float* lbuf = (float*)(smem + LB_OFF);   // [2][32]

  // ---- local max per row, exchange across halves ----
  float mrow[4], rl[4];
#pragma unroll
  for (int r = 0; r < 4; ++r) {
    const int qi = q0 + 16 * rg + 4 * lg + r;
    float m = -3.0e38f;
#pragma unroll
    for (int s = 0; s < HSUB; ++s) {
      const int ki = q0 - WIN + 16 * (ts0 + s) + lm;
      const bool ok = (ki >= 0) && (ki <= qi) && (ki > qi - WIN);
      float v = ok ? acc[s][r] : -3.0e38f;
      acc[s][r] = v;
      m = fmaxf(m, v);
    }
#pragma unroll
    for (int msk = 1; msk < 16; msk <<= 1) m = fmaxf(m, __shfl_xor(m, msk));
    mrow[r] = m;
    if (lm == 0) mbuf[hf * 32 + 16 * rg + 4 * lg + r] = m;
  }
  __syncthreads();
#pragma unroll
  for (int r = 0; r < 4; ++r)
    mrow[r] = fmaxf(mrow[r], mbuf[(1 - hf) * 32 + 16 * rg + 4 * lg + r]);

  // ---- p = exp(s-m), local l, write P (bf16), exchange l ----
#pragma unroll
  for (int r = 0; r < 4; ++r) {
    float l = 0.f;
#pragma unroll
    for (int s = 0; s < HSUB; ++s) {
      float p = __expf(acc[s][r] - mrow[r]);
      acc[s][r] = p;
      l += p;
    }
#pragma unroll
    for (int msk = 1; msk < 16; msk <<= 1) l += __shfl_xor(l, msk);
    if (lm == 0) lbuf[hf * 32 + 16 * rg + 4 * lg + r] = l;
    rl[r] = l;                            // local sum, combined after barrier
    const int row = 16 * rg + 4 * lg + r;
#pragma unroll
    for (int s = 0; s < HSUB; ++s) {
      const int col = 16 * (ts0 + s) + lm;
      *(unsigned short*)(smem + row * (PSTR * 2) + col * 2) = bfbits(acc[s][r]);
    }
  }
  __syncthreads();
#pragma unroll
  for (int r = 0; r < 4; ++r)
    rl[r] = 1.f / (rl[r] + lbuf[(1 - hf) * 32 + 16 * rg + 4 * lg + r]);

  // ---- pass 2: O[rg rows][hf d-quarter] = P V, 2-deep V prefetch ----
  f32x4 o[4];
#pragma unroll
  for (int n = 0; n < 4; ++n) o[n] = (f32x4){0.f, 0.f, 0.f, 0.f};

#pragma unroll
  for (int kc = 0; kc < 9; ++kc) {        // 32-key chunks over 288-key window
    const int keyb = q0 - WIN + 32 * kc;
    const bool live = keyb >= 0;
    bf16v8 vf[4];
    if (live) {
#pragma unroll
      for (int n = 0; n < 4; ++n) {       // consume vbuf[kc&1] into bf16 regs
        bfu8 V_;
#pragma unroll
        for (int j2 = 0; j2 < 4; ++j2)
          V_.p[j2] = bf16x2{(__bf16)vbuf[kc & 1][8 * n + 2 * j2],
                            (__bf16)vbuf[kc & 1][8 * n + 2 * j2 + 1]};
        vf[n] = V_.v;
      }
    }
    if (kc + 2 < 9) vload(kc + 2);        // re-issue the freed buffer
    if (live) {
      const bf16v8 pf = *(const bf16v8*)(smem + (16 * rg + lm) * (PSTR * 2) +
                                         (32 * kc + 8 * lg) * 2);
#pragma unroll
      for (int n = 0; n < 4; ++n) o[n] = MFMA(pf, vf[n], o[n]);
    }
  }

  // ---- epilogue: rows 4lg+r of group rg, cols d-quarter of hf ----
  float* ob = og + (size_t)(h * S + q0 + 16 * rg) * DH;
#pragma unroll
  for (int n = 0; n < 4; ++n)
#pragma unroll
    for (int r = 0; r < 4; ++r)
      ob[(4 * lg + r) * DH + 64 * hf + 16 * n + lm] = o[n][r] * rl[r];
}

extern "C" void kernel_launch(void* const* d_in, const int* in_sizes, int n_in,
                              void* d_out, int out_size, void* d_ws, size_t ws_size,
                              hipStream_t stream) {
  const float* q = (const float*)d_in[0];
  const float* k = (const float*)d_in[1];
  const float* v = (const float*)d_in[2];
  float* out = (float*)d_out;
  const int H = 8, D = 128;
  const int S = in_sizes[0] / (H * D);    // 4096
  const int nblk = (S / QB) * H;          // 1024 -> up to 4 blocks/CU
  lwa7<<<dim3(nblk), 256, 0, stream>>>(q, k, v, out, S);
}